// Round 1
// baseline (137.346 us; speedup 1.0000x reference)
//
#include <hip/hip_runtime.h>
#include <stdint.h>

#define B_ROWS  131072
#define D_DIM   512
#define BM      64
#define THREADS 256

typedef __attribute__((ext_vector_type(8))) __bf16 bf16x8;
typedef __attribute__((ext_vector_type(4))) float  f32x4;

__device__ __forceinline__ unsigned short f32_to_bf16_rne(float f) {
    uint32_t u = __builtin_bit_cast(uint32_t, f);
    u += 0x7FFFu + ((u >> 16) & 1u);
    return (unsigned short)(u >> 16);
}
__device__ __forceinline__ float bf16_bits_to_f32(unsigned short h) {
    return __builtin_bit_cast(float, ((uint32_t)h) << 16);
}

// Repack L (fp32 row-major [K=512][N=512]) into bf16 "fragment order":
// flat index = ((ks*32 + ntg)*64 + lane)*8 + e  holds  L[k][n] with
//   n = ntg*16 + (lane&15),  k = ks*32 + 8*(lane>>4) + e.
// A wave's B-fragment load for (ks, ntg) is then 64 lanes x 16B contiguous.
__global__ void prep_lt(const float* __restrict__ L, unsigned short* __restrict__ Ltf) {
    int o = blockIdx.x * 256 + threadIdx.x;
    #pragma unroll
    for (int i = 0; i < 4; ++i) {
        int idx  = o + i * 65536;
        int e    = idx & 7;
        int l    = (idx >> 3) & 63;
        int tile = idx >> 9;          // 0..511
        int ntg  = tile & 31;
        int ks   = tile >> 5;
        int n    = ntg * 16 + (l & 15);
        int k    = ks * 32 + (l >> 4) * 8 + e;
        Ltf[idx] = f32_to_bf16_rne(L[k * 512 + n]);
    }
}

__global__ __launch_bounds__(THREADS, 2)
void psd_main(const float* __restrict__ x, const unsigned short* __restrict__ Ltf,
              const float* __restrict__ b, const float* __restrict__ c,
              float* __restrict__ out) {
    __shared__ __align__(16) unsigned short As[BM * D_DIM];  // 64 KiB, XOR-swizzled
    __shared__ float wpart[4][BM];
    __shared__ float bpart[THREADS];

    const int t    = threadIdx.x;
    const int row0 = blockIdx.x * BM;
    char* AsB = (char*)As;

    // ---- stage x tile: fp32 HBM -> bf16 LDS (coalesced float4 loads) ----
    const float4* xg = (const float4*)(x + (size_t)row0 * D_DIM);
    #pragma unroll
    for (int i = 0; i < 32; ++i) {
        int f = i * THREADS + t;          // float4 index within tile [0,8192)
        float4 v = xg[f];
        int row  = f >> 7;                // 128 float4 per row
        int col4 = f & 127;
        ushort4 h;
        h.x = f32_to_bf16_rne(v.x); h.y = f32_to_bf16_rne(v.y);
        h.z = f32_to_bf16_rne(v.z); h.w = f32_to_bf16_rne(v.w);
        int byte = row * 1024 + ((col4 * 8) ^ ((row & 7) << 4));
        *(ushort4*)(AsB + byte) = h;
    }
    __syncthreads();

    const int w    = t >> 6;
    const int lane = t & 63;
    const int g    = lane >> 4;
    const int ln   = lane & 15;
    const int swz  = (ln & 7) << 4;

    f32x4 acc[4][8];
    #pragma unroll
    for (int m = 0; m < 4; ++m)
        #pragma unroll
        for (int n = 0; n < 8; ++n)
            acc[m][n] = (f32x4){0.f, 0.f, 0.f, 0.f};

    // per-(wave,lane) base into fragment-order L: element ((w*8)*64 + lane)*8
    const unsigned short* LtW = Ltf + (size_t)w * 4096 + lane * 8;

    // ---- K-loop: no barriers; A from LDS, B from L2 ----
    for (int ks = 0; ks < 16; ++ks) {
        bf16x8 a[4];
        int cb = ((ks * 64 + g * 16) ^ swz);
        #pragma unroll
        for (int m = 0; m < 4; ++m)
            a[m] = *(const bf16x8*)(AsB + (m * 16 + ln) * 1024 + cb);
        #pragma unroll
        for (int nt = 0; nt < 8; ++nt) {
            bf16x8 bf = *(const bf16x8*)(LtW + ks * 16384 + nt * 512);
            #pragma unroll
            for (int m = 0; m < 4; ++m)
                acc[m][nt] = __builtin_amdgcn_mfma_f32_16x16x32_bf16(a[m], bf, acc[m][nt], 0, 0, 0);
        }
    }

    // ---- epilogue: rowsum of squares; C/D layout col=lane&15, row=4*(lane>>4)+reg ----
    float rsum[4][4];
    #pragma unroll
    for (int m = 0; m < 4; ++m) {
        #pragma unroll
        for (int r = 0; r < 4; ++r) {
            float s = 0.f;
            #pragma unroll
            for (int nt = 0; nt < 8; ++nt) { float v = acc[m][nt][r]; s += v * v; }
            s += __shfl_xor(s, 1);
            s += __shfl_xor(s, 2);
            s += __shfl_xor(s, 4);
            s += __shfl_xor(s, 8);
            rsum[m][r] = s;
        }
    }
    if (ln == 0) {
        #pragma unroll
        for (int m = 0; m < 4; ++m)
            #pragma unroll
            for (int r = 0; r < 4; ++r)
                wpart[w][m * 16 + g * 4 + r] = rsum[m][r];
    }
    __syncthreads();

    // ---- x.b from bf16 LDS tile (wave-uniform scalar b loads) ----
    {
        const int row  = t & 63;
        const int q    = t >> 6;            // wave-uniform
        const int rswz = (row & 7) << 4;
        const float4* b4 = (const float4*)b;
        float bd = 0.f;
        #pragma unroll
        for (int j = 0; j < 32; ++j) {
            int col4 = q * 32 + j;
            float4 bb = b4[col4];
            ushort4 xb = *(const ushort4*)(AsB + row * 1024 + ((col4 * 8) ^ rswz));
            bd += bf16_bits_to_f32(xb.x) * bb.x + bf16_bits_to_f32(xb.y) * bb.y
                + bf16_bits_to_f32(xb.z) * bb.z + bf16_bits_to_f32(xb.w) * bb.w;
        }
        bpart[t] = bd;
    }
    __syncthreads();

    if (t < BM) {
        float y = wpart[0][t] + wpart[1][t] + wpart[2][t] + wpart[3][t]
                + bpart[t] + bpart[t + 64] + bpart[t + 128] + bpart[t + 192]
                + c[0];
        out[row0 + t] = y;
    }
}

extern "C" void kernel_launch(void* const* d_in, const int* in_sizes, int n_in,
                              void* d_out, int out_size, void* d_ws, size_t ws_size,
                              hipStream_t stream) {
    const float* x = (const float*)d_in[0];
    const float* L = (const float*)d_in[1];
    const float* b = (const float*)d_in[2];
    const float* c = (const float*)d_in[3];
    float* out = (float*)d_out;
    unsigned short* Ltf = (unsigned short*)d_ws;   // 512 KiB

    prep_lt<<<256, 256, 0, stream>>>(L, Ltf);
    psd_main<<<B_ROWS / BM, THREADS, 0, stream>>>(x, Ltf, b, c, out);
}

// Round 2
// 132.624 us; speedup vs baseline: 1.0356x; 1.0356x over previous
//
#include <hip/hip_runtime.h>
#include <stdint.h>

#define B_ROWS  131072
#define D_DIM   512
#define BM      64
#define THREADS 512   // 8 waves

typedef __attribute__((ext_vector_type(8))) __bf16 bf16x8;
typedef __attribute__((ext_vector_type(4))) float  f32x4;

__device__ __forceinline__ unsigned short f32_to_bf16_rne(float f) {
    uint32_t u = __builtin_bit_cast(uint32_t, f);
    u += 0x7FFFu + ((u >> 16) & 1u);
    return (unsigned short)(u >> 16);
}
__device__ __forceinline__ float bf16_bits_to_f32(unsigned short h) {
    return __builtin_bit_cast(float, ((uint32_t)h) << 16);
}

// Repack L (fp32 row-major [K=512][N=512]) into bf16 "fragment order":
// flat index = ((ks*32 + ntg)*64 + lane)*8 + e  holds  L[k][n] with
//   n = ntg*16 + (lane&15),  k = ks*32 + 8*(lane>>4) + e.
// A wave's B-fragment load for (ks, ntg) is 64 lanes x 16B contiguous.
__global__ void prep_lt(const float* __restrict__ L, unsigned short* __restrict__ Ltf) {
    int o = blockIdx.x * 256 + threadIdx.x;
    #pragma unroll
    for (int i = 0; i < 4; ++i) {
        int idx  = o + i * 65536;
        int e    = idx & 7;
        int l    = (idx >> 3) & 63;
        int tile = idx >> 9;          // 0..511
        int ntg  = tile & 31;
        int ks   = tile >> 5;
        int n    = ntg * 16 + (l & 15);
        int k    = ks * 32 + (l >> 4) * 8 + e;
        Ltf[idx] = f32_to_bf16_rne(L[k * 512 + n]);
    }
}

__global__ __launch_bounds__(THREADS, 4)
void psd_main(const float* __restrict__ x, const unsigned short* __restrict__ Ltf,
              const float* __restrict__ b, const float* __restrict__ c,
              float* __restrict__ out) {
    __shared__ __align__(16) unsigned short As[BM * D_DIM];  // 64 KiB, XOR-swizzled
    __shared__ float wpart[8][BM];
    __shared__ float bpart[THREADS];

    const int t    = threadIdx.x;
    const int row0 = blockIdx.x * BM;
    char* AsB = (char*)As;

    // ---- stage x tile: fp32 HBM -> bf16 LDS (coalesced float4 loads) ----
    const float4* xg = (const float4*)(x + (size_t)row0 * D_DIM);
    #pragma unroll
    for (int i = 0; i < 16; ++i) {
        int f = i * THREADS + t;          // float4 index within tile [0,8192)
        float4 v = xg[f];
        int row  = f >> 7;                // 128 float4 per row
        int col4 = f & 127;
        ushort4 h;
        h.x = f32_to_bf16_rne(v.x); h.y = f32_to_bf16_rne(v.y);
        h.z = f32_to_bf16_rne(v.z); h.w = f32_to_bf16_rne(v.w);
        int byte = row * 1024 + ((col4 * 8) ^ ((row & 7) << 4));
        *(ushort4*)(AsB + byte) = h;
    }
    __syncthreads();

    const int w    = t >> 6;          // wave 0..7, owns n-tiles ntg = w*4 .. w*4+3
    const int lane = t & 63;
    const int g    = lane >> 4;
    const int ln   = lane & 15;
    const int swz  = (ln & 7) << 4;

    f32x4 acc[4][4];
    #pragma unroll
    for (int m = 0; m < 4; ++m)
        #pragma unroll
        for (int n = 0; n < 4; ++n)
            acc[m][n] = (f32x4){0.f, 0.f, 0.f, 0.f};

    // per-(wave,lane) base into fragment-order L
    const unsigned short* LtW = Ltf + (size_t)w * 2048 + lane * 8;

    // ---- K-loop: no barriers; A from LDS, B from L2 ----
    for (int ks = 0; ks < 16; ++ks) {
        bf16x8 a[4];
        int cb = ((ks * 64 + g * 16) ^ swz);
        #pragma unroll
        for (int m = 0; m < 4; ++m)
            a[m] = *(const bf16x8*)(AsB + (m * 16 + ln) * 1024 + cb);
        #pragma unroll
        for (int nt = 0; nt < 4; ++nt) {
            bf16x8 bf = *(const bf16x8*)(LtW + ks * 16384 + nt * 512);
            #pragma unroll
            for (int m = 0; m < 4; ++m)
                acc[m][nt] = __builtin_amdgcn_mfma_f32_16x16x32_bf16(a[m], bf, acc[m][nt], 0, 0, 0);
        }
    }

    // ---- epilogue: rowsum of squares; C/D layout col=lane&15, row=4*(lane>>4)+reg ----
    float rsum[4][4];
    #pragma unroll
    for (int m = 0; m < 4; ++m) {
        #pragma unroll
        for (int r = 0; r < 4; ++r) {
            float s = 0.f;
            #pragma unroll
            for (int nt = 0; nt < 4; ++nt) { float v = acc[m][nt][r]; s += v * v; }
            s += __shfl_xor(s, 1);
            s += __shfl_xor(s, 2);
            s += __shfl_xor(s, 4);
            s += __shfl_xor(s, 8);
            rsum[m][r] = s;
        }
    }
    if (ln == 0) {
        #pragma unroll
        for (int m = 0; m < 4; ++m)
            #pragma unroll
            for (int r = 0; r < 4; ++r)
                wpart[w][m * 16 + g * 4 + r] = rsum[m][r];
    }
    __syncthreads();

    // ---- x.b from bf16 LDS tile (wave-uniform column range) ----
    {
        const int row  = t & 63;
        const int q    = t >> 6;            // wave-uniform, 0..7
        const int rswz = (row & 7) << 4;
        const float4* b4 = (const float4*)b;
        float bd = 0.f;
        #pragma unroll
        for (int j = 0; j < 16; ++j) {
            int col4 = q * 16 + j;
            float4 bb = b4[col4];
            ushort4 xb = *(const ushort4*)(AsB + row * 1024 + ((col4 * 8) ^ rswz));
            bd += bf16_bits_to_f32(xb.x) * bb.x + bf16_bits_to_f32(xb.y) * bb.y
                + bf16_bits_to_f32(xb.z) * bb.z + bf16_bits_to_f32(xb.w) * bb.w;
        }
        bpart[t] = bd;
    }
    __syncthreads();

    if (t < BM) {
        float y = c[0];
        #pragma unroll
        for (int k = 0; k < 8; ++k) y += wpart[k][t] + bpart[t + k * 64];
        out[row0 + t] = y;
    }
}

extern "C" void kernel_launch(void* const* d_in, const int* in_sizes, int n_in,
                              void* d_out, int out_size, void* d_ws, size_t ws_size,
                              hipStream_t stream) {
    const float* x = (const float*)d_in[0];
    const float* L = (const float*)d_in[1];
    const float* b = (const float*)d_in[2];
    const float* c = (const float*)d_in[3];
    float* out = (float*)d_out;
    unsigned short* Ltf = (unsigned short*)d_ws;   // 512 KiB

    prep_lt<<<256, 256, 0, stream>>>(L, Ltf);
    psd_main<<<B_ROWS / BM, THREADS, 0, stream>>>(x, Ltf, b, c, out);
}

// Round 3
// 104.150 us; speedup vs baseline: 1.3187x; 1.2734x over previous
//
#include <hip/hip_runtime.h>
#include <stdint.h>

#define B_ROWS  131072
#define D_DIM   512
#define BM      64
#define THREADS 512   // 8 waves

typedef __attribute__((ext_vector_type(8))) __bf16 bf16x8;
typedef __attribute__((ext_vector_type(4))) float  f32x4;

__device__ __forceinline__ unsigned short f32_to_bf16_rne(float f) {
    uint32_t u = __builtin_bit_cast(uint32_t, f);
    u += 0x7FFFu + ((u >> 16) & 1u);
    return (unsigned short)(u >> 16);
}
__device__ __forceinline__ float bf16_bits_to_f32(unsigned short h) {
    return __builtin_bit_cast(float, ((uint32_t)h) << 16);
}

// Repack L (fp32 row-major [K=512][N=512]) into bf16 "fragment order":
// flat index = ((ks*32 + ntg)*64 + lane)*8 + e  holds  L[k][n] with
//   n = ntg*16 + (lane&15),  k = ks*32 + 8*(lane>>4) + e.
__global__ void prep_lt(const float* __restrict__ L, unsigned short* __restrict__ Ltf) {
    int o = blockIdx.x * 256 + threadIdx.x;
    #pragma unroll
    for (int i = 0; i < 4; ++i) {
        int idx  = o + i * 65536;
        int e    = idx & 7;
        int l    = (idx >> 3) & 63;
        int tile = idx >> 9;          // 0..511
        int ntg  = tile & 31;
        int ks   = tile >> 5;
        int n    = ntg * 16 + (l & 15);
        int k    = ks * 32 + (l >> 4) * 8 + e;
        Ltf[idx] = f32_to_bf16_rne(L[k * 512 + n]);
    }
}

__global__ __launch_bounds__(THREADS, 4)
void psd_main(const float* __restrict__ x, const unsigned short* __restrict__ Ltf,
              const float* __restrict__ b, const float* __restrict__ c,
              float* __restrict__ out) {
    __shared__ __align__(16) unsigned short As[BM * D_DIM];  // 64 KiB, XOR-swizzled
    __shared__ float wpart[8][BM];
    __shared__ float bpart[THREADS];

    const int t    = threadIdx.x;
    const int row0 = blockIdx.x * BM;
    char* AsB = (char*)As;

    // ---- stage x tile: two batches of 8 in-flight float4 loads ----
    const float4* xg = (const float4*)(x + (size_t)row0 * D_DIM);
    {
        float4 v[8];
        #pragma unroll
        for (int h = 0; h < 2; ++h) {
            #pragma unroll
            for (int i = 0; i < 8; ++i)
                v[i] = xg[(h * 8 + i) * THREADS + t];
            #pragma unroll
            for (int i = 0; i < 8; ++i) {
                int f = (h * 8 + i) * THREADS + t;
                int row  = f >> 7;
                int col4 = f & 127;
                ushort4 hh;
                hh.x = f32_to_bf16_rne(v[i].x); hh.y = f32_to_bf16_rne(v[i].y);
                hh.z = f32_to_bf16_rne(v[i].z); hh.w = f32_to_bf16_rne(v[i].w);
                int byte = row * 1024 + ((col4 * 8) ^ ((row & 7) << 4));
                *(ushort4*)(AsB + byte) = hh;
            }
        }
    }
    __syncthreads();

    const int w    = t >> 6;          // wave 0..7, owns n-tiles ntg = w*4 .. w*4+3
    const int lane = t & 63;
    const int g    = lane >> 4;
    const int ln   = lane & 15;
    const int swz  = (ln & 7) << 4;

    f32x4 acc[4][4];
    #pragma unroll
    for (int m = 0; m < 4; ++m)
        #pragma unroll
        for (int n = 0; n < 4; ++n)
            acc[m][n] = (f32x4){0.f, 0.f, 0.f, 0.f};

    const unsigned short* LtW = Ltf + (size_t)w * 2048 + lane * 8;

    // ---- K-loop: explicit B double-buffer; full unroll -> prefetch 1 ks ahead ----
    bf16x8 bcur[4], bnxt[4];
    #pragma unroll
    for (int nt = 0; nt < 4; ++nt)
        bcur[nt] = *(const bf16x8*)(LtW + nt * 512);

    #pragma unroll
    for (int ks = 0; ks < 16; ++ks) {
        const int ks1 = (ks + 1) & 15;
        #pragma unroll
        for (int nt = 0; nt < 4; ++nt)
            bnxt[nt] = *(const bf16x8*)(LtW + ks1 * 16384 + nt * 512);

        bf16x8 a[4];
        int cb = ((ks * 64 + g * 16) ^ swz);
        #pragma unroll
        for (int m = 0; m < 4; ++m)
            a[m] = *(const bf16x8*)(AsB + (m * 16 + ln) * 1024 + cb);

        #pragma unroll
        for (int nt = 0; nt < 4; ++nt)
            #pragma unroll
            for (int m = 0; m < 4; ++m)
                acc[m][nt] = __builtin_amdgcn_mfma_f32_16x16x32_bf16(a[m], bcur[nt], acc[m][nt], 0, 0, 0);

        #pragma unroll
        for (int nt = 0; nt < 4; ++nt)
            bcur[nt] = bnxt[nt];
    }

    // ---- epilogue: rowsum of squares; C/D layout col=lane&15, row=4*(lane>>4)+reg ----
    float rsum[4][4];
    #pragma unroll
    for (int m = 0; m < 4; ++m) {
        #pragma unroll
        for (int r = 0; r < 4; ++r) {
            float s = 0.f;
            #pragma unroll
            for (int nt = 0; nt < 4; ++nt) { float v = acc[m][nt][r]; s += v * v; }
            s += __shfl_xor(s, 1);
            s += __shfl_xor(s, 2);
            s += __shfl_xor(s, 4);
            s += __shfl_xor(s, 8);
            rsum[m][r] = s;
        }
    }
    if (ln == 0) {
        #pragma unroll
        for (int m = 0; m < 4; ++m)
            #pragma unroll
            for (int r = 0; r < 4; ++r)
                wpart[w][m * 16 + g * 4 + r] = rsum[m][r];
    }
    __syncthreads();

    // ---- x.b from bf16 LDS tile (wave-uniform column range) ----
    {
        const int row  = t & 63;
        const int q    = t >> 6;            // wave-uniform, 0..7
        const int rswz = (row & 7) << 4;
        const float4* b4 = (const float4*)b;
        float bd = 0.f;
        #pragma unroll
        for (int j = 0; j < 16; ++j) {
            int col4 = q * 16 + j;
            float4 bb = b4[col4];
            ushort4 xb = *(const ushort4*)(AsB + row * 1024 + ((col4 * 8) ^ rswz));
            bd += bf16_bits_to_f32(xb.x) * bb.x + bf16_bits_to_f32(xb.y) * bb.y
                + bf16_bits_to_f32(xb.z) * bb.z + bf16_bits_to_f32(xb.w) * bb.w;
        }
        bpart[t] = bd;
    }
    __syncthreads();

    if (t < BM) {
        float y = c[0];
        #pragma unroll
        for (int k = 0; k < 8; ++k) y += wpart[k][t] + bpart[t + k * 64];
        out[row0 + t] = y;
    }
}

extern "C" void kernel_launch(void* const* d_in, const int* in_sizes, int n_in,
                              void* d_out, int out_size, void* d_ws, size_t ws_size,
                              hipStream_t stream) {
    const float* x = (const float*)d_in[0];
    const float* L = (const float*)d_in[1];
    const float* b = (const float*)d_in[2];
    const float* c = (const float*)d_in[3];
    float* out = (float*)d_out;
    unsigned short* Ltf = (unsigned short*)d_ws;   // 512 KiB

    prep_lt<<<256, 256, 0, stream>>>(L, Ltf);
    psd_main<<<B_ROWS / BM, THREADS, 0, stream>>>(x, Ltf, b, c, out);
}